// Round 1
// baseline (1153.038 us; speedup 1.0000x reference)
//
#include <hip/hip_runtime.h>

#define XMAX 1024
#define VOCAB 5000
#define BS 32
#define YMAX 128
#define LSTATES 257            // 2*YMAX+1
#define NROWS130 130           // ymax+2
#define LOGZERO_F (-1e10f)
#define PEN_F (-2e10f)
#define PF 4

// LDS layout for dp kernel
#define PLANES_BYTES (XMAX * 5 * 2 * 8)      // [t][r][2] u64 ballot bitplanes = 81920
#define ABUF_FLOATS 328                       // 2 guard + 320 states + pad
#define SARR_OFF (PLANES_BYTES + ABUF_FLOATS * 4)
#define SMEM_BYTES (SARR_OFF + XMAX * 2)      // + u16 s_arr[1024]

// ---------------------------------------------------------------------------
// Kernel 1: gather per-path log probs into lpe[b][t][257]
// ---------------------------------------------------------------------------
__global__ __launch_bounds__(256) void gather_k(const float* __restrict__ ctc,
                                                const int* __restrict__ ys,
                                                const int* __restrict__ blankp,
                                                float* __restrict__ lpe) {
    int b = blockIdx.y;
    int idx = blockIdx.x * 256 + threadIdx.x;      // grid.x = 1028 -> exactly 1024*257
    int t = idx / LSTATES;
    int l = idx - t * LSTATES;
    int blank = blankp[0];
    int col = (l & 1) ? ys[b * YMAX + (l >> 1)] : blank;
    lpe[(size_t)(b * XMAX + t) * LSTATES + l] =
        ctc[(size_t)(b * XMAX + t) * VOCAB + col];
}

// ---------------------------------------------------------------------------
// Kernel 2: Viterbi DP + backtrace. One 64-lane wave per batch element.
// ---------------------------------------------------------------------------
__global__ __launch_bounds__(64) void dp_k(const float* __restrict__ lpe,
                                           const int* __restrict__ src_size,
                                           const int* __restrict__ ys,
                                           const int* __restrict__ ylens,
                                           unsigned char* __restrict__ counts,
                                           float* __restrict__ out_ylen,
                                           float* __restrict__ out_scores) {
    extern __shared__ char smem[];
    unsigned long long* planes = (unsigned long long*)smem;          // [1024][5][2]
    float* abuf = (float*)(smem + PLANES_BYTES);                     // [328]
    unsigned short* s_arr = (unsigned short*)(smem + SARR_OFF);      // [1024]

    const int b = blockIdx.x;
    const int lane = threadIdx.x;
    const int src = src_size[b];
    const int yl = ylens[b];
    const int pl = 2 * yl + 1;

    for (int i = lane; i < ABUF_FLOATS; i += 64) abuf[i] = LOGZERO_F;
    __syncthreads();
    if (lane == 0) abuf[2] = 0.0f;     // alpha0[0] = 0
    __syncthreads();
    float* alpha = abuf + 2;           // alpha[-2..] valid via guards

    // per-(reg,lane) constant: m2 blocking penalty
    float pen[5];
    const int ysb = b * YMAX;
#pragma unroll
    for (int r = 0; r < 5; ++r) {
        int l = r * 64 + lane;
        bool blocked = true;           // even states, l<3 pads -> blocked
        if ((l & 1) && l >= 3) {
            int j = (l - 1) >> 1;
            if (j > YMAX - 1) j = YMAX - 1;     // garbage lanes (l>=257), unused
            blocked = (ys[ysb + j] == ys[ysb + j - 1]);
        }
        pen[r] = blocked ? PEN_F : 0.0f;
    }

    // alpha mirror in registers (m0)
    float av[5];
#pragma unroll
    for (int r = 0; r < 5; ++r)
        av[r] = (r == 0 && lane == 0) ? 0.0f : LOGZERO_F;

    const float* lpb = lpe + (size_t)b * XMAX * LSTATES;
    float sc1 = LOGZERO_F, sc2 = LOGZERO_F;

    auto load_row = [&](int t, float (&dst)[5]) {
        const float* row = lpb + (size_t)t * LSTATES;
#pragma unroll
        for (int r = 0; r < 5; ++r) dst[r] = row[r * 64 + lane];
    };

    auto dp_step = [&](int t, float (&lp)[5]) {
        float m1v[5], m2v[5];
#pragma unroll
        for (int r = 0; r < 5; ++r) {
            int l = r * 64 + lane;
            m2v[r] = alpha[l - 2];
            m1v[r] = alpha[l - 1];
        }
        asm volatile("" ::: "memory");   // all reads before any write (cross-lane)
        unsigned long long q0[5], q1[5];
#pragma unroll
        for (int r = 0; r < 5; ++r) {
            int l = r * 64 + lane;
            float m0 = av[r];
            float m1 = m1v[r];
            float m2 = m2v[r] + pen[r];
            float mx = fmaxf(fmaxf(m0, m1), m2);
            int d = (mx == m0) ? 0 : ((mx == m1) ? 1 : 2);
            float an = mx + lp[r];
            av[r] = an;
            alpha[l] = an;
            q0[r] = __ballot(d & 1);
            q1[r] = __ballot(d & 2);
        }
        if (lane == 0) {
#pragma unroll
            for (int r = 0; r < 5; ++r) {
                planes[(t * 5 + r) * 2] = q0[r];
                planes[(t * 5 + r) * 2 + 1] = q1[r];
            }
        }
        asm volatile("" ::: "memory");
        if (t == src - 1) {             // wave-uniform
            sc1 = alpha[pl - 1];
            sc2 = alpha[pl - 2];
        }
    };

    // prefetch ring, static indexing
    float lpf[PF][5];
#pragma unroll
    for (int p = 0; p < PF; ++p) {
        int tt = p; if (tt > src - 1) tt = src - 1;
        load_row(tt, lpf[p]);
    }

    const int nfull = src / PF;
    int t = 0;
    for (int g = 0; g < nfull; ++g) {
#pragma unroll
        for (int p = 0; p < PF; ++p) {
            dp_step(t, lpf[p]);
            int tn = t + PF; if (tn > src - 1) tn = src - 1;
            load_row(tn, lpf[p]);
            ++t;
        }
    }
    {   // tail (< PF steps); slots already hold the right rows
        const int t0 = nfull * PF;
#pragma unroll
        for (int p = 0; p < PF; ++p) {
            if (t0 + p < src) dp_step(t0 + p, lpf[p]);
        }
    }

    asm volatile("" ::: "memory");
    const int start = (sc1 > sc2) ? (pl - 1) : (pl - 2);
    const float score = fmaxf(sc1, sc2);

    // backtrace: S(t) chain via 2-bit deltas in bitplanes
    if (lane == 0) {
        int s = start;
        s_arr[src - 1] = (unsigned short)s;
        for (int tt = src - 1; tt >= 1; --tt) {
            int w = s >> 6;
            unsigned long long p0 = planes[(tt * 5 + w) * 2];
            unsigned long long p1 = planes[(tt * 5 + w) * 2 + 1];
            int bit = s & 63;
            int d = (int)((p0 >> bit) & 1ull) | (((int)((p1 >> bit) & 1ull)) << 1);
            s -= d;
            s_arr[tt - 1] = (unsigned short)s;
        }
    }
    __syncthreads();

    // counts[b][t] = #nonblank deduped labels emitted before frame t
    //             = (S(min(t-1, src-1)) + 1) >> 1   (t>0),  0 at t=0
    unsigned char* cb = counts + b * XMAX;
    for (int tt = lane; tt < XMAX; tt += 64) {
        int tc = tt - 1;
        if (tc > src - 1) tc = src - 1;
        int v = (tt == 0) ? 0 : ((s_arr[tc] + 1) >> 1);
        cb[tt] = (unsigned char)v;
    }
    if (lane == 0) {
        out_ylen[b] = (float)(yl + 1);
        out_scores[b] = score;
    }
}

// ---------------------------------------------------------------------------
// Kernel 3: build trigger_mask [bs][130][1024] as floats
// ---------------------------------------------------------------------------
__global__ __launch_bounds__(256) void mask_k(const unsigned char* __restrict__ counts,
                                              const int* __restrict__ src_size,
                                              float* __restrict__ out) {
    size_t i = (size_t)blockIdx.x * 256 + threadIdx.x;   // grid = 16640 -> exact
    int t = (int)(i & (XMAX - 1));
    int br = (int)(i >> 10);          // b*130 + r
    int r = br % NROWS130;
    int b = br / NROWS130;
    float v;
    if (r == 0) {
        v = (t == 0) ? 1.0f : 0.0f;   // sos row
    } else {
        int jj = r - 1;
        int c = counts[b * XMAX + t];
        bool on = (c == jj);
        if (jj == YMAX) on = on || (t == src_size[b] - 1);
        v = on ? 1.0f : 0.0f;
    }
    out[i] = v;
}

// ---------------------------------------------------------------------------
extern "C" void kernel_launch(void* const* d_in, const int* in_sizes, int n_in,
                              void* d_out, int out_size, void* d_ws, size_t ws_size,
                              hipStream_t stream) {
    const float* ctc      = (const float*)d_in[0];
    // d_in[1] = src_mask: all-ones by construction, unused
    const int*   src_size = (const int*)d_in[2];
    const int*   ys       = (const int*)d_in[3];
    const int*   ylens    = (const int*)d_in[4];
    const int*   blankp   = (const int*)d_in[5];
    float* out = (float*)d_out;

    float* lpe = (float*)d_ws;
    size_t lpe_elems = (size_t)BS * XMAX * LSTATES + 1024;   // +pad for r4 overread
    unsigned char* counts = (unsigned char*)(lpe + lpe_elems);

    (void)hipFuncSetAttribute((const void*)dp_k,
                              hipFuncAttributeMaxDynamicSharedMemorySize,
                              SMEM_BYTES);

    dim3 g1(1028, BS);
    gather_k<<<g1, 256, 0, stream>>>(ctc, ys, blankp, lpe);

    const size_t mask_elems = (size_t)BS * NROWS130 * XMAX;   // 4,259,840
    dp_k<<<BS, 64, SMEM_BYTES, stream>>>(lpe, src_size, ys, ylens, counts,
                                         out + mask_elems, out + mask_elems + BS);

    mask_k<<<16640, 256, 0, stream>>>(counts, src_size, out);
}